// Round 1
// 859.390 us; speedup vs baseline: 1.2790x; 1.2790x over previous
//
#include <hip/hip_runtime.h>
#include <math.h>

#define B_ 2
#define S_ 2048
#define D_ 1024
#define H_ 16
#define HD_ 64
#define BH_ (B_*H_)
#define OUT0_ (B_*S_*D_)

typedef __attribute__((ext_vector_type(8))) short bf16x8;   // 8 bf16 in 4 VGPRs
typedef __attribute__((ext_vector_type(4))) float floatx4;
typedef __attribute__((ext_vector_type(8))) short short8_t;
typedef __attribute__((ext_vector_type(4))) short short4_t;

static __device__ __forceinline__ short f2bf(float x) {
    union { float f; unsigned u; } c; c.f = x;
    unsigned r = (c.u + 0x7fffu + ((c.u >> 16) & 1u)) >> 16;
    return (short)r;
}

// ---------------------------------------------------------------------------
// fp32 -> bf16 convert, 4 elements/thread
// ---------------------------------------------------------------------------
__global__ __launch_bounds__(256) void cvt_kernel(
    const float* __restrict__ src, short* __restrict__ dst, int n4)
{
    int i = blockIdx.x * 256 + threadIdx.x;
    if (i >= n4) return;
    float4 v = *(const float4*)&src[(size_t)i * 4];
    short4_t o;
    o.x = f2bf(v.x); o.y = f2bf(v.y); o.z = f2bf(v.z); o.w = f2bf(v.w);
    *(short4_t*)&dst[(size_t)i * 4] = o;
}

// ---------------------------------------------------------------------------
// 1024x1024 fp32 -> bf16 transpose: dst[n][k] = src[k][n]
// ---------------------------------------------------------------------------
__global__ __launch_bounds__(256) void cvtT_kernel(
    const float* __restrict__ src, short* __restrict__ dst)
{
    __shared__ short Tl[64 * 72];
    const int t = threadIdx.x;
    const int r0 = blockIdx.y * 64;   // k rows
    const int c0 = blockIdx.x * 64;   // n cols
    {
        const int r = t >> 2, cq = t & 3;
#pragma unroll
        for (int u = 0; u < 4; ++u) {
            float4 v = *(const float4*)&src[(size_t)(r0 + r) * 1024 + c0 + cq * 16 + u * 4];
            Tl[r * 72 + cq * 16 + u * 4 + 0] = f2bf(v.x);
            Tl[r * 72 + cq * 16 + u * 4 + 1] = f2bf(v.y);
            Tl[r * 72 + cq * 16 + u * 4 + 2] = f2bf(v.z);
            Tl[r * 72 + cq * 16 + u * 4 + 3] = f2bf(v.w);
        }
    }
    __syncthreads();
    {
        const int c = t >> 2, rq = t & 3;
        short tmp[16];
#pragma unroll
        for (int u = 0; u < 16; ++u) tmp[u] = Tl[(rq * 16 + u) * 72 + c];
        *(short8_t*)&dst[(size_t)(c0 + c) * 1024 + r0 + rq * 16] = *(short8_t*)&tmp[0];
        *(short8_t*)&dst[(size_t)(c0 + c) * 1024 + r0 + rq * 16 + 8] = *(short8_t*)&tmp[8];
    }
}

// ---------------------------------------------------------------------------
// bf16 transpose per (b,h): Vt[bh][f][s] = Vh[bh][s][f]
// ---------------------------------------------------------------------------
__global__ __launch_bounds__(256) void transpose_v_kernel(
    const short* __restrict__ Vh, short* __restrict__ Vt)
{
    __shared__ short Tl[64 * 72];
    const int t = threadIdx.x;
    const int bh = blockIdx.y;
    const int s0 = blockIdx.x * 64;
    {
        const int r = t >> 2, cq = t & 3;  // r = s row, cq*16 = f chunk
        *(short8_t*)&Tl[r * 72 + cq * 16] =
            *(const short8_t*)&Vh[((size_t)bh * S_ + s0 + r) * HD_ + cq * 16];
        *(short8_t*)&Tl[r * 72 + cq * 16 + 8] =
            *(const short8_t*)&Vh[((size_t)bh * S_ + s0 + r) * HD_ + cq * 16 + 8];
    }
    __syncthreads();
    {
        const int f = t >> 2, rq = t & 3;
        short tmp[16];
#pragma unroll
        for (int u = 0; u < 16; ++u) tmp[u] = Tl[(rq * 16 + u) * 72 + f];
        *(short8_t*)&Vt[((size_t)bh * HD_ + f) * S_ + s0 + rq * 16] = *(short8_t*)&tmp[0];
        *(short8_t*)&Vt[((size_t)bh * HD_ + f) * S_ + s0 + rq * 16 + 8] = *(short8_t*)&tmp[8];
    }
}

// ---------------------------------------------------------------------------
// bf16 MFMA GEMM: Y = A[4096x1024] * Bt^T + bias.  Bt is [n][k] (pre-transposed).
// Tile 128x128, 4 waves (2x2), each wave 64x64 = 4x4 MFMA 16x16x32 frags.
// mode 0: fp32 out row-major [m][1024]
// mode 1: bf16 out scatter [((b*16+h)*2048+s)*64+f]  (b=m>>11,s=m&2047,h=n>>6,f=n&63)
// ---------------------------------------------------------------------------
__global__ __launch_bounds__(256) void gemm_bf16_kernel(
    const short* __restrict__ A, const short* __restrict__ Bt,
    const float* __restrict__ bias, void* __restrict__ Y, int mode)
{
    __shared__ short Al[128 * 40];
    __shared__ short Bl[128 * 40];
    const int t = threadIdx.x;
    const int w = t >> 6, lane = t & 63;
    const int quad = lane >> 4, l16 = lane & 15;
    const int wm = w >> 1, wn = w & 1;
    const int m0 = blockIdx.y * 128;
    const int n0 = blockIdx.x * 128;

    floatx4 acc[4][4] = {};

    const int r = t >> 1, h = t & 1;   // staging: row r, 16-short half h
    for (int k0 = 0; k0 < 1024; k0 += 32) {
        *(short8_t*)&Al[r * 40 + h * 16] =
            *(const short8_t*)&A[(size_t)(m0 + r) * 1024 + k0 + h * 16];
        *(short8_t*)&Al[r * 40 + h * 16 + 8] =
            *(const short8_t*)&A[(size_t)(m0 + r) * 1024 + k0 + h * 16 + 8];
        *(short8_t*)&Bl[r * 40 + h * 16] =
            *(const short8_t*)&Bt[(size_t)(n0 + r) * 1024 + k0 + h * 16];
        *(short8_t*)&Bl[r * 40 + h * 16 + 8] =
            *(const short8_t*)&Bt[(size_t)(n0 + r) * 1024 + k0 + h * 16 + 8];
        __syncthreads();
        bf16x8 a[4], b[4];
#pragma unroll
        for (int i = 0; i < 4; ++i)
            a[i] = *(const bf16x8*)&Al[(wm * 64 + i * 16 + l16) * 40 + quad * 8];
#pragma unroll
        for (int j = 0; j < 4; ++j)
            b[j] = *(const bf16x8*)&Bl[(wn * 64 + j * 16 + l16) * 40 + quad * 8];
#pragma unroll
        for (int i = 0; i < 4; ++i)
#pragma unroll
            for (int j = 0; j < 4; ++j)
                acc[i][j] = __builtin_amdgcn_mfma_f32_16x16x32_bf16(a[i], b[j], acc[i][j], 0, 0, 0);
        __syncthreads();
    }

#pragma unroll
    for (int i = 0; i < 4; ++i) {
#pragma unroll
        for (int j = 0; j < 4; ++j) {
            const int col = n0 + wn * 64 + j * 16 + l16;
            const float bcol = bias[col];
#pragma unroll
            for (int rr = 0; rr < 4; ++rr) {
                const int row = m0 + wm * 64 + i * 16 + quad * 4 + rr;
                const float v = acc[i][j][rr] + bcol;
                if (mode == 0) {
                    ((float*)Y)[(size_t)row * 1024 + col] = v;
                } else {
                    const int b = row >> 11, s = row & 2047;
                    const int hh = col >> 6, f = col & 63;
                    ((short*)Y)[(((size_t)(b * H_ + hh) * S_) + s) * HD_ + f] = f2bf(v);
                }
            }
        }
    }
}

// ---------------------------------------------------------------------------
// Pass A: per-row softmax stats (m = rowmax of s, LI = 1/sum(exp(s-m))).
// s = (Q.K)/8 recomputed tile-wise via MFMA; Q in registers, K tile in LDS.
// Grid (q0/128, bh). Online (m,l) kept per-lane; reduced across l16 then wn.
// ---------------------------------------------------------------------------
__global__ __launch_bounds__(256) void stats_kernel(
    const short* __restrict__ Qh, const short* __restrict__ Kh,
    float* __restrict__ M, float* __restrict__ LI)
{
    __shared__ short Kl[128 * 72];
    __shared__ float sm[2][128];
    __shared__ float sl[2][128];
    const int t = threadIdx.x;
    const int w = t >> 6, lane = t & 63;
    const int quad = lane >> 4, l16 = lane & 15;
    const int wm = w >> 1, wn = w & 1;
    const int bh = blockIdx.y;
    const int q0 = blockIdx.x * 128;

    bf16x8 qf[4][2];
#pragma unroll
    for (int i = 0; i < 4; ++i)
#pragma unroll
        for (int ks = 0; ks < 2; ++ks)
            qf[i][ks] = *(const bf16x8*)&Qh[((size_t)bh * S_ + q0 + wm * 64 + i * 16 + l16) * HD_ + ks * 32 + quad * 8];

    float m_p[16], l_p[16];
#pragma unroll
    for (int x = 0; x < 16; ++x) { m_p[x] = -1e30f; l_p[x] = 0.0f; }

    for (int c0 = 0; c0 < S_; c0 += 128) {
        {
            const int r = t >> 1, h2 = t & 1;
            const short* ksrc = &Kh[((size_t)bh * S_ + c0 + r) * HD_ + h2 * 32];
#pragma unroll
            for (int u = 0; u < 4; ++u)
                *(short8_t*)&Kl[r * 72 + h2 * 32 + u * 8] = *(const short8_t*)&ksrc[u * 8];
        }
        __syncthreads();
        floatx4 acc[4][4] = {};
#pragma unroll
        for (int ks = 0; ks < 2; ++ks) {
            bf16x8 b[4];
#pragma unroll
            for (int j = 0; j < 4; ++j)
                b[j] = *(const bf16x8*)&Kl[(wn * 64 + j * 16 + l16) * 72 + ks * 32 + quad * 8];
#pragma unroll
            for (int i = 0; i < 4; ++i)
#pragma unroll
                for (int j = 0; j < 4; ++j)
                    acc[i][j] = __builtin_amdgcn_mfma_f32_16x16x32_bf16(qf[i][ks], b[j], acc[i][j], 0, 0, 0);
        }
        __syncthreads();
#pragma unroll
        for (int i = 0; i < 4; ++i)
#pragma unroll
            for (int rr = 0; rr < 4; ++rr) {
                const int idx = i * 4 + rr;
                const float s0 = acc[i][0][rr] * 0.125f, s1 = acc[i][1][rr] * 0.125f;
                const float s2 = acc[i][2][rr] * 0.125f, s3 = acc[i][3][rr] * 0.125f;
                const float tm = fmaxf(fmaxf(s0, s1), fmaxf(s2, s3));
                const float mn = fmaxf(m_p[idx], tm);
                l_p[idx] = l_p[idx] * __expf(m_p[idx] - mn)
                         + __expf(s0 - mn) + __expf(s1 - mn)
                         + __expf(s2 - mn) + __expf(s3 - mn);
                m_p[idx] = mn;
            }
    }
    // reduce across the 16 column-lanes (same quad group holds same rows)
#pragma unroll
    for (int idx = 0; idx < 16; ++idx) {
#pragma unroll
        for (int off = 1; off < 16; off <<= 1) {
            const float mo = __shfl_xor(m_p[idx], off);
            const float lo = __shfl_xor(l_p[idx], off);
            const float mn = fmaxf(m_p[idx], mo);
            l_p[idx] = l_p[idx] * __expf(m_p[idx] - mn) + lo * __expf(mo - mn);
            m_p[idx] = mn;
        }
    }
    if (l16 == 0) {
#pragma unroll
        for (int i = 0; i < 4; ++i)
#pragma unroll
            for (int rr = 0; rr < 4; ++rr) {
                const int row = wm * 64 + i * 16 + quad * 4 + rr;
                sm[wn][row] = m_p[i * 4 + rr];
                sl[wn][row] = l_p[i * 4 + rr];
            }
    }
    __syncthreads();
    if (t < 128) {
        const float m0v = sm[0][t], m1v = sm[1][t];
        const float mn = fmaxf(m0v, m1v);
        const float l = sl[0][t] * __expf(m0v - mn) + sl[1][t] * __expf(m1v - mn);
        M[(size_t)bh * S_ + q0 + t] = mn;
        LI[(size_t)bh * S_ + q0 + t] = 1.0f / l;
    }
}

// ---------------------------------------------------------------------------
// Pass B: fused scores -> softmax-apply -> attn write (once, nontemporal)
//         -> P.V accumulate -> CTX bf16.
// Grid (q0/128, bh).  Scores waves 2x2 over (q,c); PV waves 4x over q.
// ---------------------------------------------------------------------------
#define PPAD 136
#define VPAD 136
__global__ __launch_bounds__(256) void fused_attn_kernel(
    const short* __restrict__ Qh, const short* __restrict__ Kh,
    const short* __restrict__ Vt, const float* __restrict__ M,
    const float* __restrict__ LI, float* __restrict__ attn,
    short* __restrict__ CTX)
{
    __shared__ short Kl[128 * 72];
    __shared__ short Pl[128 * PPAD];
    __shared__ short Vl[64 * VPAD];
    const int t = threadIdx.x;
    const int w = t >> 6, lane = t & 63;
    const int quad = lane >> 4, l16 = lane & 15;
    const int wm = w >> 1, wn = w & 1;
    const int bh = blockIdx.y;
    const int q0 = blockIdx.x * 128;
    const int b = bh >> 4, hh = bh & 15;

    bf16x8 qf[4][2];
#pragma unroll
    for (int i = 0; i < 4; ++i)
#pragma unroll
        for (int ks = 0; ks < 2; ++ks)
            qf[i][ks] = *(const bf16x8*)&Qh[((size_t)bh * S_ + q0 + wm * 64 + i * 16 + l16) * HD_ + ks * 32 + quad * 8];

    float m_r[16], li_r[16];
#pragma unroll
    for (int i = 0; i < 4; ++i)
#pragma unroll
        for (int rr = 0; rr < 4; ++rr) {
            const int row = q0 + wm * 64 + i * 16 + quad * 4 + rr;
            m_r[i * 4 + rr]  = M[(size_t)bh * S_ + row];
            li_r[i * 4 + rr] = LI[(size_t)bh * S_ + row];
        }

    floatx4 acc2[2][4] = {};

    for (int c0 = 0; c0 < S_; c0 += 128) {
        {   // stage K tile: 128 rows x 64 shorts
            const int r = t >> 1, h2 = t & 1;
            const short* ksrc = &Kh[((size_t)bh * S_ + c0 + r) * HD_ + h2 * 32];
#pragma unroll
            for (int u = 0; u < 4; ++u)
                *(short8_t*)&Kl[r * 72 + h2 * 32 + u * 8] = *(const short8_t*)&ksrc[u * 8];
        }
        {   // stage V tile: 64 f-rows x 128 keys (coalesced from Vt)
            const int f = t >> 2, part = t & 3;
            const short* vsrc = &Vt[((size_t)bh * HD_ + f) * S_ + c0 + part * 32];
#pragma unroll
            for (int u = 0; u < 4; ++u)
                *(short8_t*)&Vl[f * VPAD + part * 32 + u * 8] = *(const short8_t*)&vsrc[u * 8];
        }
        __syncthreads();

        floatx4 acc[4][4] = {};
#pragma unroll
        for (int ks = 0; ks < 2; ++ks) {
            bf16x8 bfr[4];
#pragma unroll
            for (int j = 0; j < 4; ++j)
                bfr[j] = *(const bf16x8*)&Kl[(wn * 64 + j * 16 + l16) * 72 + ks * 32 + quad * 8];
#pragma unroll
            for (int i = 0; i < 4; ++i)
#pragma unroll
                for (int j = 0; j < 4; ++j)
                    acc[i][j] = __builtin_amdgcn_mfma_f32_16x16x32_bf16(qf[i][ks], bfr[j], acc[i][j], 0, 0, 0);
        }

        // softmax-apply: p = exp(s - m)/l, write attn (never re-read -> nt),
        // pack bf16 P into LDS for the PV MFMA
#pragma unroll
        for (int i = 0; i < 4; ++i)
#pragma unroll
            for (int rr = 0; rr < 4; ++rr) {
                const int idx = i * 4 + rr;
                const int row = wm * 64 + i * 16 + quad * 4 + rr;
                float* adst = &attn[((size_t)bh * S_ + q0 + row) * S_ + c0 + wn * 64 + l16];
                short* pdst = &Pl[row * PPAD + wn * 64 + l16];
#pragma unroll
                for (int j = 0; j < 4; ++j) {
                    const float p = __expf(acc[i][j][rr] * 0.125f - m_r[idx]) * li_r[idx];
                    __builtin_nontemporal_store(p, &adst[j * 16]);
                    pdst[j * 16] = f2bf(p);
                }
            }
        __syncthreads();

        // PV: each wave owns 32 q rows; k-loop over the 128 keys of this tile
#pragma unroll
        for (int ks2 = 0; ks2 < 4; ++ks2) {
            bf16x8 a2[2], bv[4];
#pragma unroll
            for (int i = 0; i < 2; ++i)
                a2[i] = *(const bf16x8*)&Pl[(w * 32 + i * 16 + l16) * PPAD + ks2 * 32 + quad * 8];
#pragma unroll
            for (int j = 0; j < 4; ++j)
                bv[j] = *(const bf16x8*)&Vl[(j * 16 + l16) * VPAD + ks2 * 32 + quad * 8];
#pragma unroll
            for (int i = 0; i < 2; ++i)
#pragma unroll
                for (int j = 0; j < 4; ++j)
                    acc2[i][j] = __builtin_amdgcn_mfma_f32_16x16x32_bf16(a2[i], bv[j], acc2[i][j], 0, 0, 0);
        }
        __syncthreads();
    }

#pragma unroll
    for (int i = 0; i < 2; ++i)
#pragma unroll
        for (int j = 0; j < 4; ++j) {
            const int col = j * 16 + l16;
#pragma unroll
            for (int rr = 0; rr < 4; ++rr) {
                const int s = q0 + w * 32 + i * 16 + quad * 4 + rr;
                CTX[((size_t)(b * S_ + s)) * 1024 + hh * 64 + col] = f2bf(acc2[i][j][rr]);
            }
        }
}

extern "C" void kernel_launch(void* const* d_in, const int* in_sizes, int n_in,
                              void* d_out, int out_size, void* d_ws, size_t ws_size,
                              hipStream_t stream)
{
    const float* Xq  = (const float*)d_in[0];
    const float* Xkv = (const float*)d_in[1];
    const float* Wq  = (const float*)d_in[2];
    const float* bq  = (const float*)d_in[3];
    const float* Wk  = (const float*)d_in[4];
    const float* bk  = (const float*)d_in[5];
    const float* Wv  = (const float*)d_in[6];
    const float* bv  = (const float*)d_in[7];
    const float* Wo  = (const float*)d_in[8];
    const float* bo  = (const float*)d_in[9];

    float* out  = (float*)d_out;
    float* attn = out + OUT0_;

    short* ws = (short*)d_ws;
    short* XQB  = ws;                  // 4M shorts (dead after QKV gemms)
    short* XKVB = ws + 4194304;
    short* WQT  = ws + 8388608;        // 1M each
    short* WKT  = ws + 9437184;
    short* WVT  = ws + 10485760;
    short* WOT  = ws + 11534336;
    short* QH   = ws + 12582912;       // [BH][S][HD] bf16, 4M each
    short* KH   = ws + 16777216;
    short* VH   = ws + 20971520;
    short* VT   = ws + 25165824;       // [BH][HD][S]
    short* CTXB = ws + 29360128;       // [B*S][1024]
    // softmax stats reuse the XQB region (dead once QKV gemms have run)
    float* Mst  = (float*)ws;                 // 64K floats = 256 KB
    float* LIst = (float*)(ws + 131072);      // next 256 KB

    dim3 blk(256);

    cvt_kernel<<<dim3(4096), blk, 0, stream>>>(Xq,  XQB,  1048576);
    cvt_kernel<<<dim3(4096), blk, 0, stream>>>(Xkv, XKVB, 1048576);
    cvtT_kernel<<<dim3(16, 16), blk, 0, stream>>>(Wq, WQT);
    cvtT_kernel<<<dim3(16, 16), blk, 0, stream>>>(Wk, WKT);
    cvtT_kernel<<<dim3(16, 16), blk, 0, stream>>>(Wv, WVT);
    cvtT_kernel<<<dim3(16, 16), blk, 0, stream>>>(Wo, WOT);

    gemm_bf16_kernel<<<dim3(8, 32), blk, 0, stream>>>(XQB,  WQT, bq, QH, 1);
    gemm_bf16_kernel<<<dim3(8, 32), blk, 0, stream>>>(XKVB, WKT, bk, KH, 1);
    gemm_bf16_kernel<<<dim3(8, 32), blk, 0, stream>>>(XKVB, WVT, bv, VH, 1);

    transpose_v_kernel<<<dim3(32, 32), blk, 0, stream>>>(VH, VT);

    stats_kernel<<<dim3(16, 32), blk, 0, stream>>>(QH, KH, Mst, LIst);
    fused_attn_kernel<<<dim3(16, 32), blk, 0, stream>>>(QH, KH, VT, Mst, LIst, attn, CTXB);

    gemm_bf16_kernel<<<dim3(8, 32), blk, 0, stream>>>(CTXB, WOT, bo, out, 0);

    (void)in_sizes; (void)n_in; (void)out_size; (void)ws_size;
}

// Round 2
// 831.534 us; speedup vs baseline: 1.3219x; 1.0335x over previous
//
#include <hip/hip_runtime.h>
#include <math.h>

#define B_ 2
#define S_ 2048
#define D_ 1024
#define H_ 16
#define HD_ 64
#define BH_ (B_*H_)
#define OUT0_ (B_*S_*D_)

typedef __attribute__((ext_vector_type(8))) short bf16x8;   // 8 bf16 in 4 VGPRs
typedef __attribute__((ext_vector_type(4))) float floatx4;
typedef __attribute__((ext_vector_type(8))) short short8_t;
typedef __attribute__((ext_vector_type(4))) short short4_t;

static __device__ __forceinline__ short f2bf(float x) {
    union { float f; unsigned u; } c; c.f = x;
    unsigned r = (c.u + 0x7fffu + ((c.u >> 16) & 1u)) >> 16;
    return (short)r;
}

// async global->LDS, 16B per lane; LDS dest = wave-uniform base + lane*16
static __device__ __forceinline__ void gload16(const short* g, short* l) {
    __builtin_amdgcn_global_load_lds(
        (const __attribute__((address_space(1))) unsigned int*)g,
        (__attribute__((address_space(3))) unsigned int*)l, 16, 0, 0);
}

// ---------------------------------------------------------------------------
// fp32 -> bf16 convert, 4 elements/thread
// ---------------------------------------------------------------------------
__global__ __launch_bounds__(256) void cvt_kernel(
    const float* __restrict__ src, short* __restrict__ dst, int n4)
{
    int i = blockIdx.x * 256 + threadIdx.x;
    if (i >= n4) return;
    float4 v = *(const float4*)&src[(size_t)i * 4];
    short4_t o;
    o.x = f2bf(v.x); o.y = f2bf(v.y); o.z = f2bf(v.z); o.w = f2bf(v.w);
    *(short4_t*)&dst[(size_t)i * 4] = o;
}

// ---------------------------------------------------------------------------
// 1024x1024 fp32 -> bf16 transpose: dst[n][k] = src[k][n]
// ---------------------------------------------------------------------------
__global__ __launch_bounds__(256) void cvtT_kernel(
    const float* __restrict__ src, short* __restrict__ dst)
{
    __shared__ short Tl[64 * 72];
    const int t = threadIdx.x;
    const int r0 = blockIdx.y * 64;   // k rows
    const int c0 = blockIdx.x * 64;   // n cols
    {
        const int r = t >> 2, cq = t & 3;
#pragma unroll
        for (int u = 0; u < 4; ++u) {
            float4 v = *(const float4*)&src[(size_t)(r0 + r) * 1024 + c0 + cq * 16 + u * 4];
            Tl[r * 72 + cq * 16 + u * 4 + 0] = f2bf(v.x);
            Tl[r * 72 + cq * 16 + u * 4 + 1] = f2bf(v.y);
            Tl[r * 72 + cq * 16 + u * 4 + 2] = f2bf(v.z);
            Tl[r * 72 + cq * 16 + u * 4 + 3] = f2bf(v.w);
        }
    }
    __syncthreads();
    {
        const int c = t >> 2, rq = t & 3;
        short tmp[16];
#pragma unroll
        for (int u = 0; u < 16; ++u) tmp[u] = Tl[(rq * 16 + u) * 72 + c];
        *(short8_t*)&dst[(size_t)(c0 + c) * 1024 + r0 + rq * 16] = *(short8_t*)&tmp[0];
        *(short8_t*)&dst[(size_t)(c0 + c) * 1024 + r0 + rq * 16 + 8] = *(short8_t*)&tmp[8];
    }
}

// ---------------------------------------------------------------------------
// bf16 transpose per (b,h): Vt[bh][f][s] = Vh[bh][s][f]
// ---------------------------------------------------------------------------
__global__ __launch_bounds__(256) void transpose_v_kernel(
    const short* __restrict__ Vh, short* __restrict__ Vt)
{
    __shared__ short Tl[64 * 72];
    const int t = threadIdx.x;
    const int bh = blockIdx.y;
    const int s0 = blockIdx.x * 64;
    {
        const int r = t >> 2, cq = t & 3;
        *(short8_t*)&Tl[r * 72 + cq * 16] =
            *(const short8_t*)&Vh[((size_t)bh * S_ + s0 + r) * HD_ + cq * 16];
        *(short8_t*)&Tl[r * 72 + cq * 16 + 8] =
            *(const short8_t*)&Vh[((size_t)bh * S_ + s0 + r) * HD_ + cq * 16 + 8];
    }
    __syncthreads();
    {
        const int f = t >> 2, rq = t & 3;
        short tmp[16];
#pragma unroll
        for (int u = 0; u < 16; ++u) tmp[u] = Tl[(rq * 16 + u) * 72 + f];
        *(short8_t*)&Vt[((size_t)bh * HD_ + f) * S_ + s0 + rq * 16] = *(short8_t*)&tmp[0];
        *(short8_t*)&Vt[((size_t)bh * HD_ + f) * S_ + s0 + rq * 16 + 8] = *(short8_t*)&tmp[8];
    }
}

// ---------------------------------------------------------------------------
// bf16 MFMA GEMM (m97 structure): Y = A[4096x1024] * Bt^T + bias.
// Linear 128x32 LDS tiles staged via global_load_lds width=16.
// Tile 128x128, 4 waves (2x2), each wave 64x64 = 4x4 MFMA 16x16x32 frags.
// mode 0: fp32 out row-major [m][1024]
// mode 1: bf16 out scatter [((b*16+h)*2048+s)*64+f]
// ---------------------------------------------------------------------------
__global__ __launch_bounds__(256) void gemm_bf16_kernel(
    const short* __restrict__ A, const short* __restrict__ Bt,
    const float* __restrict__ bias, void* __restrict__ Y, int mode)
{
    __shared__ __attribute__((aligned(16))) short Al[128 * 32];
    __shared__ __attribute__((aligned(16))) short Bl[128 * 32];
    const int t = threadIdx.x;
    const int w = t >> 6, lane = t & 63;
    const int quad = lane >> 4, l16 = lane & 15;
    const int wm = w >> 1, wn = w & 1;

    // XCD-aware bijective swizzle: group n-panels of nearby m-rows per XCD
    const int nwg = gridDim.x * gridDim.y;           // 256 (divisible by 8)
    const int cpx = nwg >> 3;
    const int id0 = blockIdx.y * gridDim.x + blockIdx.x;
    const int lid = (id0 & 7) * cpx + (id0 >> 3);
    const int n0 = (lid % gridDim.x) * 128;
    const int m0 = (lid / gridDim.x) * 128;

    floatx4 acc[4][4] = {};

    const int r_a = lane >> 2;            // row within 16-row segment
    const int kc  = (lane & 3) * 8;       // 16B chunk within 64B row

    for (int k0 = 0; k0 < 1024; k0 += 32) {
        // stage A: 128 rows x 32 shorts; wave w covers segments w and w+4
        gload16(&A[(size_t)(m0 + w * 16 + r_a) * 1024 + k0 + kc],      &Al[w * 512]);
        gload16(&A[(size_t)(m0 + 64 + w * 16 + r_a) * 1024 + k0 + kc], &Al[2048 + w * 512]);
        gload16(&Bt[(size_t)(n0 + w * 16 + r_a) * 1024 + k0 + kc],      &Bl[w * 512]);
        gload16(&Bt[(size_t)(n0 + 64 + w * 16 + r_a) * 1024 + k0 + kc], &Bl[2048 + w * 512]);
        __syncthreads();
        bf16x8 a[4], b[4];
#pragma unroll
        for (int i = 0; i < 4; ++i)
            a[i] = *(const bf16x8*)&Al[(wm * 64 + i * 16 + l16) * 32 + quad * 8];
#pragma unroll
        for (int j = 0; j < 4; ++j)
            b[j] = *(const bf16x8*)&Bl[(wn * 64 + j * 16 + l16) * 32 + quad * 8];
#pragma unroll
        for (int i = 0; i < 4; ++i)
#pragma unroll
            for (int j = 0; j < 4; ++j)
                acc[i][j] = __builtin_amdgcn_mfma_f32_16x16x32_bf16(a[i], b[j], acc[i][j], 0, 0, 0);
        __syncthreads();
    }

#pragma unroll
    for (int i = 0; i < 4; ++i) {
#pragma unroll
        for (int j = 0; j < 4; ++j) {
            const int col = n0 + wn * 64 + j * 16 + l16;
            const float bcol = bias[col];
#pragma unroll
            for (int rr = 0; rr < 4; ++rr) {
                const int row = m0 + wm * 64 + i * 16 + quad * 4 + rr;
                const float v = acc[i][j][rr] + bcol;
                if (mode == 0) {
                    ((float*)Y)[(size_t)row * 1024 + col] = v;
                } else {
                    const int b2 = row >> 11, s = row & 2047;
                    const int hh = col >> 6, f = col & 63;
                    ((short*)Y)[(((size_t)(b2 * H_ + hh) * S_) + s) * HD_ + f] = f2bf(v);
                }
            }
        }
    }
}

// ---------------------------------------------------------------------------
// Pass A: per-row softmax stats, SWAPPED operands: acc = mfma(K, Q).
// Per lane: q = wm*64 + i*16 + l16 (4 rows), 16 key-values per (i, c-tile).
// Reduce over keys: in-lane 16, then shfl over quad (16,32), then wn via LDS.
// ---------------------------------------------------------------------------
__global__ __launch_bounds__(256) void stats_kernel(
    const short* __restrict__ Qh, const short* __restrict__ Kh,
    float* __restrict__ M, float* __restrict__ LI)
{
    __shared__ short Kl[128 * 72];
    __shared__ float sm[2][128];
    __shared__ float sl[2][128];
    const int t = threadIdx.x;
    const int w = t >> 6, lane = t & 63;
    const int quad = lane >> 4, l16 = lane & 15;
    const int wm = w >> 1, wn = w & 1;

    // XCD swizzle: 512 blocks = 8 * 64; same-bh q-tiles land on one XCD
    const int id0 = blockIdx.y * gridDim.x + blockIdx.x;
    const int lid = (id0 & 7) * 64 + (id0 >> 3);
    const int bh = lid >> 4;
    const int q0 = (lid & 15) * 128;

    bf16x8 qf[4][2];
#pragma unroll
    for (int i = 0; i < 4; ++i)
#pragma unroll
        for (int ks = 0; ks < 2; ++ks)
            qf[i][ks] = *(const bf16x8*)&Qh[((size_t)bh * S_ + q0 + wm * 64 + i * 16 + l16) * HD_ + ks * 32 + quad * 8];

    float m_p[4], l_p[4];
#pragma unroll
    for (int x = 0; x < 4; ++x) { m_p[x] = -1e30f; l_p[x] = 0.0f; }

    for (int c0 = 0; c0 < S_; c0 += 128) {
        {
            const int r = t >> 1, h2 = t & 1;
            const short* ksrc = &Kh[((size_t)bh * S_ + c0 + r) * HD_ + h2 * 32];
#pragma unroll
            for (int u = 0; u < 4; ++u)
                *(short8_t*)&Kl[r * 72 + h2 * 32 + u * 8] = *(const short8_t*)&ksrc[u * 8];
        }
        __syncthreads();
        floatx4 acc[4][4] = {};
#pragma unroll
        for (int ks = 0; ks < 2; ++ks) {
            bf16x8 kf[4];
#pragma unroll
            for (int j = 0; j < 4; ++j)
                kf[j] = *(const bf16x8*)&Kl[(wn * 64 + j * 16 + l16) * 72 + ks * 32 + quad * 8];
#pragma unroll
            for (int i = 0; i < 4; ++i)
#pragma unroll
                for (int j = 0; j < 4; ++j)
                    acc[i][j] = __builtin_amdgcn_mfma_f32_16x16x32_bf16(kf[j], qf[i][ks], acc[i][j], 0, 0, 0);
        }
        __syncthreads();
#pragma unroll
        for (int i = 0; i < 4; ++i) {
            float s[16];
#pragma unroll
            for (int j = 0; j < 4; ++j)
#pragma unroll
                for (int rr = 0; rr < 4; ++rr) s[j * 4 + rr] = acc[i][j][rr] * 0.125f;
            float tm = s[0];
#pragma unroll
            for (int x = 1; x < 16; ++x) tm = fmaxf(tm, s[x]);
            const float mn = fmaxf(m_p[i], tm);
            float add = 0.0f;
#pragma unroll
            for (int x = 0; x < 16; ++x) add += __expf(s[x] - mn);
            l_p[i] = l_p[i] * __expf(m_p[i] - mn) + add;
            m_p[i] = mn;
        }
    }
    // reduce across quad lanes (same q, different key quarters)
#pragma unroll
    for (int i = 0; i < 4; ++i) {
#pragma unroll
        for (int off = 16; off < 64; off <<= 1) {
            const float mo = __shfl_xor(m_p[i], off);
            const float lo = __shfl_xor(l_p[i], off);
            const float mn = fmaxf(m_p[i], mo);
            l_p[i] = l_p[i] * __expf(m_p[i] - mn) + lo * __expf(mo - mn);
            m_p[i] = mn;
        }
    }
    if (quad == 0) {
#pragma unroll
        for (int i = 0; i < 4; ++i) {
            sm[wn][wm * 64 + i * 16 + l16] = m_p[i];
            sl[wn][wm * 64 + i * 16 + l16] = l_p[i];
        }
    }
    __syncthreads();
    if (t < 128) {
        const float m0v = sm[0][t], m1v = sm[1][t];
        const float mn = fmaxf(m0v, m1v);
        const float l = sl[0][t] * __expf(m0v - mn) + sl[1][t] * __expf(m1v - mn);
        M[(size_t)bh * S_ + q0 + t] = mn;
        LI[(size_t)bh * S_ + q0 + t] = 1.0f / l;
    }
}

// ---------------------------------------------------------------------------
// Pass B: fused scores (SWAPPED: acc = mfma(K, Q) -> lane holds 4 consecutive
// keys for one q) -> softmax-apply -> attn float4 nontemporal write ->
// P bf16 ds_write_b64 -> P.V accumulate -> CTX bf16.
// ---------------------------------------------------------------------------
#define PPAD 136
#define VPAD 136
__global__ __launch_bounds__(256) void fused_attn_kernel(
    const short* __restrict__ Qh, const short* __restrict__ Kh,
    const short* __restrict__ Vt, const float* __restrict__ M,
    const float* __restrict__ LI, float* __restrict__ attn,
    short* __restrict__ CTX)
{
    __shared__ short Kl[128 * 72];
    __shared__ short Pl[128 * PPAD];
    __shared__ short Vl[64 * VPAD];
    const int t = threadIdx.x;
    const int w = t >> 6, lane = t & 63;
    const int quad = lane >> 4, l16 = lane & 15;
    const int wm = w >> 1, wn = w & 1;

    const int id0 = blockIdx.y * gridDim.x + blockIdx.x;
    const int lid = (id0 & 7) * 64 + (id0 >> 3);
    const int bh = lid >> 4;
    const int q0 = (lid & 15) * 128;
    const int b = bh >> 4, hh = bh & 15;

    bf16x8 qf[4][2];
#pragma unroll
    for (int i = 0; i < 4; ++i)
#pragma unroll
        for (int ks = 0; ks < 2; ++ks)
            qf[i][ks] = *(const bf16x8*)&Qh[((size_t)bh * S_ + q0 + wm * 64 + i * 16 + l16) * HD_ + ks * 32 + quad * 8];

    float m_r[4], li_r[4];
#pragma unroll
    for (int i = 0; i < 4; ++i) {
        const int row = q0 + wm * 64 + i * 16 + l16;
        m_r[i]  = M[(size_t)bh * S_ + row];
        li_r[i] = LI[(size_t)bh * S_ + row];
    }

    floatx4 acc2[2][4] = {};

    for (int c0 = 0; c0 < S_; c0 += 128) {
        {   // stage K tile
            const int r = t >> 1, h2 = t & 1;
            const short* ksrc = &Kh[((size_t)bh * S_ + c0 + r) * HD_ + h2 * 32];
#pragma unroll
            for (int u = 0; u < 4; ++u)
                *(short8_t*)&Kl[r * 72 + h2 * 32 + u * 8] = *(const short8_t*)&ksrc[u * 8];
        }
        {   // stage V tile
            const int f = t >> 2, part = t & 3;
            const short* vsrc = &Vt[((size_t)bh * HD_ + f) * S_ + c0 + part * 32];
#pragma unroll
            for (int u = 0; u < 4; ++u)
                *(short8_t*)&Vl[f * VPAD + part * 32 + u * 8] = *(const short8_t*)&vsrc[u * 8];
        }
        __syncthreads();

        floatx4 acc[4][4] = {};
#pragma unroll
        for (int ks = 0; ks < 2; ++ks) {
            bf16x8 kf[4];
#pragma unroll
            for (int j = 0; j < 4; ++j)
                kf[j] = *(const bf16x8*)&Kl[(wn * 64 + j * 16 + l16) * 72 + ks * 32 + quad * 8];
#pragma unroll
            for (int i = 0; i < 4; ++i)
#pragma unroll
                for (int j = 0; j < 4; ++j)
                    acc[i][j] = __builtin_amdgcn_mfma_f32_16x16x32_bf16(kf[j], qf[i][ks], acc[i][j], 0, 0, 0);
        }

        // softmax-apply: per lane 4 consecutive keys of one q-row
#pragma unroll
        for (int i = 0; i < 4; ++i) {
            const int qrow = wm * 64 + i * 16 + l16;
#pragma unroll
            for (int j = 0; j < 4; ++j) {
                const int col = wn * 64 + j * 16 + quad * 4;
                floatx4 pv;
                short4_t ps;
#pragma unroll
                for (int rr = 0; rr < 4; ++rr) {
                    const float p = __expf(fmaf(acc[i][j][rr], 0.125f, -m_r[i])) * li_r[i];
                    pv[rr] = p; ps[rr] = f2bf(p);
                }
                __builtin_nontemporal_store(pv,
                    (floatx4*)&attn[((size_t)bh * S_ + q0 + qrow) * S_ + c0 + col]);
                *(short4_t*)&Pl[qrow * PPAD + col] = ps;
            }
        }
        __syncthreads();

        // PV: each wave owns 32 q rows; k-loop over the 128 keys of this tile
#pragma unroll
        for (int ks2 = 0; ks2 < 4; ++ks2) {
            bf16x8 a2[2], bv[4];
#pragma unroll
            for (int i = 0; i < 2; ++i)
                a2[i] = *(const bf16x8*)&Pl[(w * 32 + i * 16 + l16) * PPAD + ks2 * 32 + quad * 8];
#pragma unroll
            for (int j = 0; j < 4; ++j)
                bv[j] = *(const bf16x8*)&Vl[(j * 16 + l16) * VPAD + ks2 * 32 + quad * 8];
#pragma unroll
            for (int i = 0; i < 2; ++i)
#pragma unroll
                for (int j = 0; j < 4; ++j)
                    acc2[i][j] = __builtin_amdgcn_mfma_f32_16x16x32_bf16(a2[i], bv[j], acc2[i][j], 0, 0, 0);
        }
        __syncthreads();
    }

#pragma unroll
    for (int i = 0; i < 2; ++i)
#pragma unroll
        for (int j = 0; j < 4; ++j) {
            const int col = j * 16 + l16;
#pragma unroll
            for (int rr = 0; rr < 4; ++rr) {
                const int s = q0 + w * 32 + i * 16 + quad * 4 + rr;
                CTX[((size_t)(b * S_ + s)) * 1024 + hh * 64 + col] = f2bf(acc2[i][j][rr]);
            }
        }
}

extern "C" void kernel_launch(void* const* d_in, const int* in_sizes, int n_in,
                              void* d_out, int out_size, void* d_ws, size_t ws_size,
                              hipStream_t stream)
{
    const float* Xq  = (const float*)d_in[0];
    const float* Xkv = (const float*)d_in[1];
    const float* Wq  = (const float*)d_in[2];
    const float* bq  = (const float*)d_in[3];
    const float* Wk  = (const float*)d_in[4];
    const float* bk  = (const float*)d_in[5];
    const float* Wv  = (const float*)d_in[6];
    const float* bv  = (const float*)d_in[7];
    const float* Wo  = (const float*)d_in[8];
    const float* bo  = (const float*)d_in[9];

    float* out  = (float*)d_out;
    float* attn = out + OUT0_;

    short* ws = (short*)d_ws;
    short* XQB  = ws;                  // 4M shorts (dead after QKV gemms)
    short* XKVB = ws + 4194304;
    short* WQT  = ws + 8388608;        // 1M each
    short* WKT  = ws + 9437184;
    short* WVT  = ws + 10485760;
    short* WOT  = ws + 11534336;
    short* QH   = ws + 12582912;       // [BH][S][HD] bf16, 4M each
    short* KH   = ws + 16777216;
    short* VH   = ws + 20971520;
    short* VT   = ws + 25165824;       // [BH][HD][S]
    short* CTXB = ws + 29360128;       // [B*S][1024]
    // softmax stats reuse the XQB region (dead once QKV gemms have run)
    float* Mst  = (float*)ws;                 // 64K floats = 256 KB
    float* LIst = (float*)(ws + 131072);      // next 256 KB

    dim3 blk(256);

    cvt_kernel<<<dim3(4096), blk, 0, stream>>>(Xq,  XQB,  1048576);
    cvt_kernel<<<dim3(4096), blk, 0, stream>>>(Xkv, XKVB, 1048576);
    cvtT_kernel<<<dim3(16, 16), blk, 0, stream>>>(Wq, WQT);
    cvtT_kernel<<<dim3(16, 16), blk, 0, stream>>>(Wk, WKT);
    cvtT_kernel<<<dim3(16, 16), blk, 0, stream>>>(Wv, WVT);
    cvtT_kernel<<<dim3(16, 16), blk, 0, stream>>>(Wo, WOT);

    gemm_bf16_kernel<<<dim3(8, 32), blk, 0, stream>>>(XQB,  WQT, bq, QH, 1);
    gemm_bf16_kernel<<<dim3(8, 32), blk, 0, stream>>>(XKVB, WKT, bk, KH, 1);
    gemm_bf16_kernel<<<dim3(8, 32), blk, 0, stream>>>(XKVB, WVT, bv, VH, 1);

    transpose_v_kernel<<<dim3(32, 32), blk, 0, stream>>>(VH, VT);

    stats_kernel<<<dim3(16, 32), blk, 0, stream>>>(QH, KH, Mst, LIst);
    fused_attn_kernel<<<dim3(16, 32), blk, 0, stream>>>(QH, KH, VT, Mst, LIst, attn, CTXB);

    gemm_bf16_kernel<<<dim3(8, 32), blk, 0, stream>>>(CTXB, WOT, bo, out, 0);

    (void)in_sizes; (void)n_in; (void)out_size; (void)ws_size;
}